// Round 8
// baseline (328.009 us; speedup 1.0000x reference)
//
#include <hip/hip_runtime.h>

#define N_NODES 100000
#define N_EDGES 3200000
#define D 64
#define EPS 1e-5f

#define BSHIFT 7
#define BNODES 128                                          // nodes per bucket
#define NBUCK ((N_NODES + BNODES - 1) / BNODES)             // 782
#define P1_CHUNK 4096
#define NB_P1 ((N_EDGES + P1_CHUNK - 1) / P1_CHUNK)         // 782
#define SRC_MASK 0x1FFFFu                                   // 17 bits >= 100000
#define BCAP 4480                                           // bucket region cap
#define TBL_STRIDE 784                                      // 783 entries + pad

typedef _Float16 f16x8 __attribute__((ext_vector_type(8)));  // 8 fp16 = 4 VGPRs
typedef _Float16 half2v __attribute__((ext_vector_type(2))); // packed fp16 pair
typedef unsigned int u32x4 __attribute__((ext_vector_type(4))); // native vec for nt-store
typedef __attribute__((ext_vector_type(4))) float f32x4;

__device__ __forceinline__ unsigned short f2h(float f) {
  return __builtin_bit_cast(unsigned short, (_Float16)f);    // v_cvt_f16_f32 (RNE)
}
__device__ __forceinline__ half2v u2h(unsigned int u) {
  return __builtin_bit_cast(half2v, u);
}
__device__ __forceinline__ unsigned int h2u(half2v h) {
  return __builtin_bit_cast(unsigned int, h);
}
__device__ __forceinline__ float2 hpair(unsigned int u) {
  half2v h = __builtin_bit_cast(half2v, u);
  return make_float2((float)h.x, (float)h.y);
}
// packed fp16 accumulate: 4x v_pk_add_f16 per uint4
__device__ __forceinline__ void addp(half2v a[4], uint4 u) {
  a[0] += u2h(u.x);
  a[1] += u2h(u.y);
  a[2] += u2h(u.z);
  a[3] += u2h(u.w);
}

// ---------------------------------------------------------------------------
// blocks 0,1: fold GCNConv+FC into 64x64, emit MFMA-B-swizzled fp16 + bc.
// block 2: zero BN stat accumulators (256 floats, PACKED — R14/R16 showed
// line-padded atomic targets cost ~40us; wave-coalesced packed lines win).
// ---------------------------------------------------------------------------
__global__ __launch_bounds__(256) void combine_weights(
    const float* __restrict__ W1, const float* __restrict__ b1,
    const float* __restrict__ fw1, const float* __restrict__ fb1,
    const float* __restrict__ W2, const float* __restrict__ b2,
    const float* __restrict__ fw2, const float* __restrict__ fb2,
    unsigned int* __restrict__ WcB1, float* __restrict__ bc1,
    unsigned int* __restrict__ WcB2, float* __restrict__ bc2,
    float* __restrict__ stats) {
  if (blockIdx.x == 2) {
    if (threadIdx.x < 256) stats[threadIdx.x] = 0.0f;
    return;
  }
  const float* W  = blockIdx.x ? W2  : W1;
  const float* fw = blockIdx.x ? fw2 : fw1;
  const float* b  = blockIdx.x ? b2  : b1;
  const float* fb = blockIdx.x ? fb2 : fb1;
  unsigned int* WcB = blockIdx.x ? WcB2 : WcB1;
  float* bc = blockIdx.x ? bc2 : bc1;

  __shared__ float sW[64 * 64];
  __shared__ float sf[64 * 64];
  __shared__ float sC[64 * 64];
  for (int i = threadIdx.x; i < 4096; i += 256) { sW[i] = W[i]; sf[i] = fw[i]; }
  __syncthreads();
  for (int o = threadIdx.x; o < 4096; o += 256) {
    int i = o >> 6, j = o & 63;
    float acc = 0.f;
    #pragma unroll
    for (int k = 0; k < 64; ++k) acc += sW[i * 64 + k] * sf[k * 64 + j];
    sC[o] = acc;
  }
  __syncthreads();
  // B-fragment swizzle: frag f=(nt*2+kh), lane L, elem j -> B[(L>>4)*8+j+kh*32][nt*16+(L&15)]
  for (int o = threadIdx.x; o < 2048; o += 256) {
    int jj = o & 3, L = (o >> 2) & 63, kh = (o >> 8) & 1, nt = o >> 9;
    int k0 = (L >> 4) * 8 + jj * 2 + kh * 32;
    int n  = nt * 16 + (L & 15);
    unsigned int lo = f2h(sC[k0 * 64 + n]);
    unsigned int hi = f2h(sC[(k0 + 1) * 64 + n]);
    WcB[o] = (hi << 16) | lo;
  }
  if (threadIdx.x < 64) {
    int j = threadIdx.x;
    float acc = fb[j];
    #pragma unroll
    for (int k = 0; k < 64; ++k) acc += b[k] * sf[k * 64 + j];
    bc[j] = acc;
  }
}

// ---------------------------------------------------------------------------
// Pass 1: block-local counting sort of a 4096-edge chunk by 128-node bucket.
// R22: LDS-ladder scan (16 barriers) -> wave shfl_up scan + wsum exchange
// (2 barriers). Outputs bitwise-identical.
// ---------------------------------------------------------------------------
__global__ __launch_bounds__(256) void pass1_sort(
    const int* __restrict__ src, const int* __restrict__ dst,
    unsigned int* __restrict__ stage, unsigned short* __restrict__ tbl) {
  __shared__ unsigned int hist[NBUCK];
  __shared__ unsigned int wsum4[4];
  __shared__ unsigned int sorted[P1_CHUNK];
  const int tid = threadIdx.x;
  const int wvid = tid >> 6, ln = tid & 63;
  const int e0 = blockIdx.x * P1_CHUNK;

  for (int b = tid; b < NBUCK; b += 256) hist[b] = 0;
  __syncthreads();

  int dreg[16];                               // dst cached -> no second dst read
  #pragma unroll
  for (int k = 0; k < 16; ++k) {
    int e = e0 + k * 256 + tid;
    int d = (e < N_EDGES) ? dst[e] : -1;
    dreg[k] = d;
    if (d >= 0) atomicAdd(&hist[((unsigned)d) >> BSHIFT], 1u);
  }
  __syncthreads();

  unsigned int v[4], run = 0;
  #pragma unroll
  for (int j = 0; j < 4; ++j) {
    int bk = 4 * tid + j;
    unsigned int h = (bk < NBUCK) ? hist[bk] : 0u;
    v[j] = run;
    run += h;
  }
  // wave-level inclusive scan of run
  unsigned int inc = run;
  #pragma unroll
  for (int o = 1; o < 64; o <<= 1) {
    unsigned int t = __shfl_up(inc, o, 64);
    if (ln >= o) inc += t;
  }
  if (ln == 63) wsum4[wvid] = inc;
  __syncthreads();
  unsigned int wbase = 0, mtot = 0;
  #pragma unroll
  for (int k = 0; k < 4; ++k) {
    unsigned int s = wsum4[k];
    mtot += s;
    if (k < wvid) wbase += s;
  }
  const unsigned int excl = wbase + inc - run;
  const unsigned int m = mtot;
  unsigned short* trow = tbl + (size_t)blockIdx.x * TBL_STRIDE;
  #pragma unroll
  for (int j = 0; j < 4; ++j) {
    int bk = 4 * tid + j;
    if (bk < NBUCK) {
      unsigned int o = excl + v[j];
      hist[bk] = o;
      trow[bk] = (unsigned short)o;
    }
  }
  if (tid == 0) trow[NBUCK] = (unsigned short)m;
  __syncthreads();

  #pragma unroll
  for (int k = 0; k < 16; ++k) {
    int e = e0 + k * 256 + tid;
    int t = dreg[k];
    if (t >= 0) {
      unsigned int pos = atomicAdd(&hist[((unsigned)t) >> BSHIFT], 1u);
      sorted[pos] = (((unsigned)(t & (BNODES - 1))) << 17) | (unsigned)src[e];
    }
  }
  __syncthreads();

  unsigned int* so = stage + (size_t)blockIdx.x * P1_CHUNK;
  for (int i = tid; i < (int)m; i += 256) so[i] = sorted[i];
}

// ---------------------------------------------------------------------------
// Pass 2: paired-segment gather, LDS counting sort to node CSR. Emits eSrc,
// off, edeg, dinv, and the fused layer-1 prescale Xs (fp16).
// R22: shfl_up scans (32 barriers -> 4), batch-4 MLP gather, float4 prescale.
// ---------------------------------------------------------------------------
__global__ __launch_bounds__(512) void pass2_sort(
    const unsigned int* __restrict__ stage, const unsigned short* __restrict__ tbl,
    int* __restrict__ eSrc, int* __restrict__ off, int* __restrict__ edeg,
    float* __restrict__ dinv, const float* __restrict__ x,
    unsigned short* __restrict__ Xs) {
  __shared__ int cnt[BNODES];
  __shared__ int wsum8[8];
  __shared__ int csum2[2];
  __shared__ float dinvL[BNODES];
  __shared__ unsigned int raw[BCAP];
  __shared__ int sorted[BCAP];
  const int b = blockIdx.x, tid = threadIdx.x;
  const int wvid = tid >> 6, ln = tid & 63;
  const int n0 = b * BNODES;

  int base0 = 0, base1 = 0, len0 = 0, len1 = 0;
  {
    int s0 = 2 * tid, s1 = 2 * tid + 1;
    if (s0 < NB_P1) {
      const unsigned short* trow = tbl + (size_t)s0 * TBL_STRIDE;
      int o0 = trow[b], o1 = trow[b + 1];
      base0 = s0 * P1_CHUNK + o0;
      len0 = o1 - o0;
    }
    if (s1 < NB_P1) {
      const unsigned short* trow = tbl + (size_t)s1 * TBL_STRIDE;
      int o0 = trow[b], o1 = trow[b + 1];
      base1 = s1 * P1_CHUNK + o0;
      len1 = o1 - o0;
    }
  }
  if (tid < BNODES) cnt[tid] = 0;
  const int mylen = len0 + len1;

  // 512-wide scan via wave shfl + wsum exchange (was 18 barriers)
  int inc = mylen;
  #pragma unroll
  for (int o = 1; o < 64; o <<= 1) {
    int t = __shfl_up(inc, o, 64);
    if (ln >= o) inc += t;
  }
  if (ln == 63) wsum8[wvid] = inc;
  __syncthreads();
  int wbase = 0, mtot = 0;
  #pragma unroll
  for (int k = 0; k < 8; ++k) {
    int s = wsum8[k];
    mtot += s;
    if (k < wvid) wbase += s;
  }
  const int m = mtot;
  const int pref = wbase + inc - mylen;

  // batch-4 gather: 4 loads issued before use -> 4x MLP on L2/L3 latency
  {
    int j = 0;
    for (; j + 4 <= len0; j += 4) {
      unsigned int p0 = stage[base0 + j],     p1 = stage[base0 + j + 1];
      unsigned int p2 = stage[base0 + j + 2], p3 = stage[base0 + j + 3];
      raw[pref + j] = p0; raw[pref + j + 1] = p1;
      raw[pref + j + 2] = p2; raw[pref + j + 3] = p3;
      atomicAdd(&cnt[p0 >> 17], 1); atomicAdd(&cnt[p1 >> 17], 1);
      atomicAdd(&cnt[p2 >> 17], 1); atomicAdd(&cnt[p3 >> 17], 1);
    }
    for (; j < len0; ++j) {
      unsigned int p = stage[base0 + j];
      raw[pref + j] = p;
      atomicAdd(&cnt[p >> 17], 1);
    }
  }
  {
    const int pb = pref + len0;
    int j = 0;
    for (; j + 4 <= len1; j += 4) {
      unsigned int p0 = stage[base1 + j],     p1 = stage[base1 + j + 1];
      unsigned int p2 = stage[base1 + j + 2], p3 = stage[base1 + j + 3];
      raw[pb + j] = p0; raw[pb + j + 1] = p1;
      raw[pb + j + 2] = p2; raw[pb + j + 3] = p3;
      atomicAdd(&cnt[p0 >> 17], 1); atomicAdd(&cnt[p1 >> 17], 1);
      atomicAdd(&cnt[p2 >> 17], 1); atomicAdd(&cnt[p3 >> 17], 1);
    }
    for (; j < len1; ++j) {
      unsigned int p = stage[base1 + j];
      raw[pb + j] = p;
      atomicAdd(&cnt[p >> 17], 1);
    }
  }
  __syncthreads();

  // 128-entry scan via 2-wave shfl (was 14 barriers)
  int v = (tid < BNODES) ? cnt[tid] : 0;
  int cin = v;
  #pragma unroll
  for (int o = 1; o < 64; o <<= 1) {
    int t = __shfl_up(cin, o, 64);
    if (ln >= o) cin += t;
  }
  if (tid < BNODES && ln == 63) csum2[wvid] = cin;
  __syncthreads();
  if (tid < BNODES) {
    int incl = cin + ((wvid == 1) ? csum2[0] : 0);
    int excl = incl - v;
    int node = n0 + tid;
    float dv = rsqrtf((float)v + 1.0f);
    dinvL[tid] = dv;
    if (node < N_NODES) {
      off[node]  = b * BCAP + excl;
      edeg[node] = v;
      dinv[node] = dv;
    }
    cnt[tid] = excl;
  }
  __syncthreads();

  for (int i = tid; i < m; i += 512) {
    unsigned int p = raw[i];
    int pos = atomicAdd(&cnt[p >> 17], 1);
    if (pos < BCAP) sorted[pos] = (int)(p & SRC_MASK);
  }
  __syncthreads();

  int* out = eSrc + (size_t)b * BCAP;
  for (int i = tid; i < m; i += 512) out[i] = sorted[i];

  // fused L1 prescale, float4-vectorized (4x fewer instrs than scalar)
  const int rows = min(BNODES, N_NODES - n0);
  for (int i = tid; i < rows * 16; i += 512) {
    int r = i >> 4, c = i & 15;
    float4 xv = ((const float4*)x)[(size_t)(n0 + r) * 16 + c];
    float dv = dinvL[r];
    ushort4 o;
    o.x = f2h(dv * xv.x);
    o.y = f2h(dv * xv.y);
    o.z = f2h(dv * xv.z);
    o.w = f2h(dv * xv.w);
    ((ushort4*)Xs)[(size_t)(n0 + r) * 16 + c] = o;
  }
}

// ---------------------------------------------------------------------------
// CSR aggregation (v6.1: nbase arg, 2 dispatches of 50K nodes each — R22
// diagnostic split so the true second-tier kernels surface in rocprof top-5;
// waves remain fully independent, R21 lesson).
// ---------------------------------------------------------------------------
__global__ __launch_bounds__(256) void agg_csr(
    const int* __restrict__ off, const int* __restrict__ edeg,
    const int* __restrict__ eSrc, const unsigned short* __restrict__ Xs,
    const float* __restrict__ dinv, unsigned short* __restrict__ agg,
    int nbase) {
  const int wv = (blockIdx.x * 256 + threadIdx.x) >> 6;    // wave id
  const int lane = threadIdx.x & 63;
  const int half = lane >> 5;                              // node select
  const int l32 = lane & 31;
  const int grp = l32 >> 3;                                // 4 groups of 8
  const int sub = lane & 7;
  const int node = nbase + wv * 2 + half;
  if (node >= N_NODES) return;

  const int s0 = off[node];
  const int deg = edeg[node];
  const float dvf = dinv[node];                            // early, overlaps
  const uint4* XsV = (const uint4*)Xs;

  // coalesced index preload: lane l32 holds eSrc[s0+l32] (clamped)
  int eidx = node;
  if (deg > 0) {
    int li = (l32 < deg) ? l32 : deg - 1;
    eidx = __builtin_nontemporal_load(&eSrc[s0 + li]);
  }

  // self row: only group 0 of each half keeps it
  half2v acc[4];
  {
    uint4 u = XsV[(size_t)node * 8 + sub];
    if (l32 >= 8) { u.x = 0; u.y = 0; u.z = 0; u.w = 0; }
    acc[0] = u2h(u.x);
    acc[1] = u2h(u.y);
    acc[2] = u2h(u.z);
    acc[3] = u2h(u.w);
  }

  // 8 gather slots, straight-line: slot j covers edges j*4+grp (0..31).
  uint4 g[8];
  #pragma unroll
  for (int j = 0; j < 8; ++j) {
    int srcn = __shfl(eidx, half * 32 + j * 4 + grp, 64);
    g[j] = XsV[(size_t)srcn * 8 + sub];
  }
  #pragma unroll
  for (int j = 0; j < 8; ++j) {
    uint4 u = g[j];
    if (j * 4 + grp >= deg) { u.x = 0; u.y = 0; u.z = 0; u.w = 0; }
    addp(acc, u);
  }

  // rare fallback: deg > 32
  if (deg > 32) {
    const int lim = deg - 1;
    for (int e = 32; e < deg; e += 4) {
      int ee = e + grp;
      int srcn = __builtin_nontemporal_load(&eSrc[s0 + min(ee, lim)]);
      uint4 u = XsV[(size_t)srcn * 8 + sub];
      if (ee > lim) { u.x = 0; u.y = 0; u.z = 0; u.w = 0; }
      addp(acc, u);
    }
  }

  // cross-group packed reduce within each 32-lane half: 2 rounds
  #pragma unroll
  for (int mk = 8; mk <= 16; mk <<= 1) {
    #pragma unroll
    for (int i = 0; i < 4; ++i)
      acc[i] += u2h(__shfl_xor(h2u(acc[i]), mk, 64));
  }

  if (l32 < 8) {
    _Float16 dh = (_Float16)dvf;
    half2v d2 = {dh, dh};
    u32x4 o;
    o.x = h2u(acc[0] * d2);
    o.y = h2u(acc[1] * d2);
    o.z = h2u(acc[2] * d2);
    o.w = h2u(acc[3] * d2);
    __builtin_nontemporal_store(o, (u32x4*)(agg + (size_t)node * 64 + sub * 8));
  }
}

// ---------------------------------------------------------------------------
// MFMA GEMM: Yb(fp16)[128-row block] = A(fp16) @ WcB + bc, fused col stats.
// Packed contiguous stat atomics (R12-proven; padding regresses ~40us).
// ---------------------------------------------------------------------------
__global__ __launch_bounds__(256) void gemm_stats(
    const unsigned short* __restrict__ A, const unsigned int* __restrict__ WcB,
    const float* __restrict__ bc, unsigned short* __restrict__ Yb,
    float* __restrict__ colsum, float* __restrict__ colsq) {
  const int tid = threadIdx.x;
  const int L = tid & 63, wv = tid >> 6;
  const int quad = L >> 4, l16 = L & 15;

  const f16x8* Wv = (const f16x8*)WcB;
  f16x8 bfr[4][2];
  #pragma unroll
  for (int nt = 0; nt < 4; ++nt)
    #pragma unroll
    for (int kh = 0; kh < 2; ++kh)
      bfr[nt][kh] = Wv[(nt * 2 + kh) * 64 + L];
  float bcv[4];
  #pragma unroll
  for (int nt = 0; nt < 4; ++nt) bcv[nt] = bc[nt * 16 + l16];

  const f16x8* Av = (const f16x8*)A;
  float psum[4] = {0.f, 0.f, 0.f, 0.f}, psq[4] = {0.f, 0.f, 0.f, 0.f};

  #pragma unroll
  for (int loop = 0; loop < 2; ++loop) {
    const int rowbase = blockIdx.x * 128 + loop * 64 + wv * 16;
    const int m = min(rowbase + l16, N_NODES - 1);
    f16x8 a0 = Av[(size_t)m * 8 + quad];
    f16x8 a1 = Av[(size_t)m * 8 + 4 + quad];
    #pragma unroll
    for (int nt = 0; nt < 4; ++nt) {
      f32x4 acc = {0.f, 0.f, 0.f, 0.f};
      acc = __builtin_amdgcn_mfma_f32_16x16x32_f16(a0, bfr[nt][0], acc, 0, 0, 0);
      acc = __builtin_amdgcn_mfma_f32_16x16x32_f16(a1, bfr[nt][1], acc, 0, 0, 0);
      #pragma unroll
      for (int r = 0; r < 4; ++r) {
        int row = rowbase + quad * 4 + r;
        if (row < N_NODES) {
          float y = acc[r] + bcv[nt];
          Yb[(size_t)row * 64 + nt * 16 + l16] = f2h(y);
          psum[nt] += y;
          psq[nt] += y * y;
        }
      }
    }
  }

  #pragma unroll
  for (int nt = 0; nt < 4; ++nt) {
    psum[nt] += __shfl_xor(psum[nt], 16, 64);
    psum[nt] += __shfl_xor(psum[nt], 32, 64);
    psq[nt]  += __shfl_xor(psq[nt], 16, 64);
    psq[nt]  += __shfl_xor(psq[nt], 32, 64);
  }
  __shared__ float rsum[4][64];
  __shared__ float rsq[4][64];
  if (L < 16) {
    #pragma unroll
    for (int nt = 0; nt < 4; ++nt) {
      rsum[wv][nt * 16 + L] = psum[nt];
      rsq[wv][nt * 16 + L]  = psq[nt];
    }
  }
  __syncthreads();
  if (tid < 64) {
    float s = rsum[0][tid] + rsum[1][tid] + rsum[2][tid] + rsum[3][tid];
    float q = rsq[0][tid] + rsq[1][tid] + rsq[2][tid] + rsq[3][tid];
    atomicAdd(&colsum[tid], s);
    atomicAdd(&colsq[tid], q);
  }
}

// ---------------------------------------------------------------------------
// prescale_y (vectorized, uint4 = 8 fp16 per thread):
//   Xout = fp16( dinv[row] * relu(Yin*a1+c1) )
// ---------------------------------------------------------------------------
__global__ __launch_bounds__(256) void prescale_y(
    const unsigned short* __restrict__ Yin, unsigned short* __restrict__ Xout,
    const float* __restrict__ dinv,
    const float* __restrict__ colsum, const float* __restrict__ colsq,
    const float* __restrict__ g, const float* __restrict__ bt) {
  __shared__ float sa[64], sc[64];
  if (threadIdx.x < 64) {
    int j = threadIdx.x;
    float mu = colsum[j] * (1.0f / N_NODES);
    float var = colsq[j] * (1.0f / N_NODES) - mu * mu;
    float s = rsqrtf(var + EPS) * g[j];
    sa[j] = s;
    sc[j] = bt[j] - mu * s;
  }
  __syncthreads();
  int idx = blockIdx.x * blockDim.x + threadIdx.x;     // uint4 index
  if (idx < N_NODES * 8) {
    int r = idx >> 3, c0 = (idx & 7) * 8;
    float dv = dinv[r];
    uint4 u = ((const uint4*)Yin)[idx];
    float2 p0 = hpair(u.x), p1 = hpair(u.y), p2 = hpair(u.z), p3 = hpair(u.w);
    p0.x = dv * fmaxf(fmaf(p0.x, sa[c0    ], sc[c0    ]), 0.f);
    p0.y = dv * fmaxf(fmaf(p0.y, sa[c0 + 1], sc[c0 + 1]), 0.f);
    p1.x = dv * fmaxf(fmaf(p1.x, sa[c0 + 2], sc[c0 + 2]), 0.f);
    p1.y = dv * fmaxf(fmaf(p1.y, sa[c0 + 3], sc[c0 + 3]), 0.f);
    p2.x = dv * fmaxf(fmaf(p2.x, sa[c0 + 4], sc[c0 + 4]), 0.f);
    p2.y = dv * fmaxf(fmaf(p2.y, sa[c0 + 5], sc[c0 + 5]), 0.f);
    p3.x = dv * fmaxf(fmaf(p3.x, sa[c0 + 6], sc[c0 + 6]), 0.f);
    p3.y = dv * fmaxf(fmaf(p3.y, sa[c0 + 7], sc[c0 + 7]), 0.f);
    uint4 o;
    o.x = ((unsigned)f2h(p0.y) << 16) | f2h(p0.x);
    o.y = ((unsigned)f2h(p1.y) << 16) | f2h(p1.x);
    o.z = ((unsigned)f2h(p2.y) << 16) | f2h(p2.x);
    o.w = ((unsigned)f2h(p3.y) << 16) | f2h(p3.x);
    ((uint4*)Xout)[idx] = o;
  }
}

// ---------------------------------------------------------------------------
// final_norm (vectorized): out = fp32 relu(Yb*a2 + c2), 8 elems per thread
// ---------------------------------------------------------------------------
__global__ __launch_bounds__(256) void final_norm(
    const unsigned short* __restrict__ Yb, float* __restrict__ out,
    const float* __restrict__ colsum, const float* __restrict__ colsq,
    const float* __restrict__ g, const float* __restrict__ bt) {
  __shared__ float sa[64], sc[64];
  if (threadIdx.x < 64) {
    int j = threadIdx.x;
    float mu = colsum[j] * (1.0f / N_NODES);
    float var = colsq[j] * (1.0f / N_NODES) - mu * mu;
    float s = rsqrtf(var + EPS) * g[j];
    sa[j] = s;
    sc[j] = bt[j] - mu * s;
  }
  __syncthreads();
  int idx = blockIdx.x * blockDim.x + threadIdx.x;     // uint4 index
  if (idx < N_NODES * 8) {
    int c0 = (idx & 7) * 8;
    uint4 u = ((const uint4*)Yb)[idx];
    float2 p0 = hpair(u.x), p1 = hpair(u.y), p2 = hpair(u.z), p3 = hpair(u.w);
    float4 o0, o1;
    o0.x = fmaxf(fmaf(p0.x, sa[c0    ], sc[c0    ]), 0.f);
    o0.y = fmaxf(fmaf(p0.y, sa[c0 + 1], sc[c0 + 1]), 0.f);
    o0.z = fmaxf(fmaf(p1.x, sa[c0 + 2], sc[c0 + 2]), 0.f);
    o0.w = fmaxf(fmaf(p1.y, sa[c0 + 3], sc[c0 + 3]), 0.f);
    o1.x = fmaxf(fmaf(p2.x, sa[c0 + 4], sc[c0 + 4]), 0.f);
    o1.y = fmaxf(fmaf(p2.y, sa[c0 + 5], sc[c0 + 5]), 0.f);
    o1.z = fmaxf(fmaf(p3.x, sa[c0 + 6], sc[c0 + 6]), 0.f);
    o1.w = fmaxf(fmaf(p3.y, sa[c0 + 7], sc[c0 + 7]), 0.f);
    ((float4*)out)[idx * 2] = o0;
    ((float4*)out)[idx * 2 + 1] = o1;
  }
}

extern "C" void kernel_launch(void* const* d_in, const int* in_sizes, int n_in,
                              void* d_out, int out_size, void* d_ws, size_t ws_size,
                              hipStream_t stream) {
  const float* x   = (const float*)d_in[0];
  const int*   src = (const int*)d_in[1];          // edge_index row 0
  const int*   dst = src + N_EDGES;                // edge_index row 1
  const float* W1  = (const float*)d_in[2];
  const float* b1  = (const float*)d_in[3];
  const float* fw1 = (const float*)d_in[4];
  const float* fb1 = (const float*)d_in[5];
  const float* g1  = (const float*)d_in[6];
  const float* bt1 = (const float*)d_in[7];
  const float* W2  = (const float*)d_in[8];
  const float* b2  = (const float*)d_in[9];
  const float* fw2 = (const float*)d_in[10];
  const float* fb2 = (const float*)d_in[11];
  const float* g2  = (const float*)d_in[12];
  const float* bt2 = (const float*)d_in[13];

  float* out = (float*)d_out;                      // N x 64 fp32

  // workspace (~43 MB). aggb aliases stage; XsYb doubles as the fp16 Y buffer.
  unsigned char* w = (unsigned char*)d_ws;
  unsigned int*   stage = (unsigned int*)w;              // NB_P1*4096 uints
  unsigned short* aggb  = (unsigned short*)w;            // N*64 fp16 (alias)
  size_t ofs = ((size_t)NB_P1 * P1_CHUNK * 4 + 255) & ~(size_t)255;
  float*          dinv  = (float*)(w + ofs);             // N floats
  unsigned short* XsYb  = (unsigned short*)(dinv + N_NODES);          // N*64 fp16
  int*            eSrc  = (int*)(XsYb + (size_t)N_NODES * D);         // NBUCK*BCAP ints
  int*            off   = eSrc + (size_t)NBUCK * BCAP;   // N ints
  int*            edeg  = off + N_NODES;                 // N ints
  unsigned short* tbl   = (unsigned short*)(edeg + N_NODES);          // NB_P1*784 ushort
  unsigned int* WcB1 = (unsigned int*)(tbl + (size_t)NB_P1 * TBL_STRIDE); // 2048
  float* bc1  = (float*)(WcB1 + 2048);             // 64
  unsigned int* WcB2 = (unsigned int*)(bc1 + 64);  // 2048
  float* bc2  = (float*)(WcB2 + 2048);             // 64
  float* sum1 = bc2 + 64;                          // 64  (sum1..sq2 contiguous 256)
  float* sq1  = sum1 + 64;
  float* sum2 = sq1 + 64;
  float* sq2  = sum2 + 64;

  const int nv = N_NODES * 8;                      // uint4 count for elementwise
  const int nagg2 = 6250;                          // 50000 nodes / (4 waves x 2)
  dim3 blk(256);

  // 1. weight fold + stats zero (3 blocks)
  combine_weights<<<3, blk, 0, stream>>>(W1, b1, fw1, fb1, W2, b2, fw2, fb2,
                                         WcB1, bc1, WcB2, bc2, sum1);
  // 2-3. partition: block-local sort -> per-bucket node CSR (+L1 prescale)
  pass1_sort<<<NB_P1, blk, 0, stream>>>(src, dst, stage, tbl);
  pass2_sort<<<NBUCK, 512, 0, stream>>>(stage, tbl, eSrc, off, edeg, dinv, x, XsYb);
  // 4-6. layer 1 (agg split 2x for rocprof top-5 visibility, R22)
  agg_csr<<<nagg2, blk, 0, stream>>>(off, edeg, eSrc, XsYb, dinv, aggb, 0);
  agg_csr<<<nagg2, blk, 0, stream>>>(off, edeg, eSrc, XsYb, dinv, aggb, 50000);
  gemm_stats<<<(N_NODES + 127) / 128, blk, 0, stream>>>(aggb, WcB1, bc1, XsYb, sum1, sq1);
  prescale_y<<<(nv + 255) / 256, blk, 0, stream>>>(XsYb, XsYb, dinv, sum1, sq1, g1, bt1);
  // 7-9. layer 2
  agg_csr<<<nagg2, blk, 0, stream>>>(off, edeg, eSrc, XsYb, dinv, aggb, 0);
  agg_csr<<<nagg2, blk, 0, stream>>>(off, edeg, eSrc, XsYb, dinv, aggb, 50000);
  gemm_stats<<<(N_NODES + 127) / 128, blk, 0, stream>>>(aggb, WcB2, bc2, XsYb, sum2, sq2);
  final_norm<<<(nv + 255) / 256, blk, 0, stream>>>(XsYb, out, sum2, sq2, g2, bt2);
}

// Round 10
// 322.654 us; speedup vs baseline: 1.0166x; 1.0166x over previous
//
#include <hip/hip_runtime.h>

#define N_NODES 100000
#define N_EDGES 3200000
#define D 64
#define EPS 1e-5f

#define BSHIFT 7
#define BNODES 128                                          // nodes per bucket
#define NBUCK ((N_NODES + BNODES - 1) / BNODES)             // 782
#define P1_CHUNK 4096
#define NB_P1 ((N_EDGES + P1_CHUNK - 1) / P1_CHUNK)         // 782
#define SRC_MASK 0x1FFFFu                                   // 17 bits >= 100000
#define BCAP 4480                                           // bucket region cap
#define TBL_STRIDE 784                                      // 783 entries + pad

typedef _Float16 f16x8 __attribute__((ext_vector_type(8)));  // 8 fp16 = 4 VGPRs
typedef _Float16 half2v __attribute__((ext_vector_type(2))); // packed fp16 pair
typedef unsigned int u32x4 __attribute__((ext_vector_type(4))); // native vec for nt-store
typedef __attribute__((ext_vector_type(4))) float f32x4;

__device__ __forceinline__ unsigned short f2h(float f) {
  return __builtin_bit_cast(unsigned short, (_Float16)f);    // v_cvt_f16_f32 (RNE)
}
__device__ __forceinline__ half2v u2h(unsigned int u) {
  return __builtin_bit_cast(half2v, u);
}
__device__ __forceinline__ unsigned int h2u(half2v h) {
  return __builtin_bit_cast(unsigned int, h);
}
__device__ __forceinline__ float2 hpair(unsigned int u) {
  half2v h = __builtin_bit_cast(half2v, u);
  return make_float2((float)h.x, (float)h.y);
}
// packed fp16 accumulate: 4x v_pk_add_f16 per uint4
__device__ __forceinline__ void addp(half2v a[4], uint4 u) {
  a[0] += u2h(u.x);
  a[1] += u2h(u.y);
  a[2] += u2h(u.z);
  a[3] += u2h(u.w);
}

// ---------------------------------------------------------------------------
// blocks 0,1: fold GCNConv+FC into 64x64, emit MFMA-B-swizzled fp16 + bc.
// block 2: zero BN stat accumulators (256 floats, PACKED).
// ---------------------------------------------------------------------------
__global__ __launch_bounds__(256) void combine_weights(
    const float* __restrict__ W1, const float* __restrict__ b1,
    const float* __restrict__ fw1, const float* __restrict__ fb1,
    const float* __restrict__ W2, const float* __restrict__ b2,
    const float* __restrict__ fw2, const float* __restrict__ fb2,
    unsigned int* __restrict__ WcB1, float* __restrict__ bc1,
    unsigned int* __restrict__ WcB2, float* __restrict__ bc2,
    float* __restrict__ stats) {
  if (blockIdx.x == 2) {
    if (threadIdx.x < 256) stats[threadIdx.x] = 0.0f;
    return;
  }
  const float* W  = blockIdx.x ? W2  : W1;
  const float* fw = blockIdx.x ? fw2 : fw1;
  const float* b  = blockIdx.x ? b2  : b1;
  const float* fb = blockIdx.x ? fb2 : fb1;
  unsigned int* WcB = blockIdx.x ? WcB2 : WcB1;
  float* bc = blockIdx.x ? bc2 : bc1;

  __shared__ float sW[64 * 64];
  __shared__ float sf[64 * 64];
  __shared__ float sC[64 * 64];
  for (int i = threadIdx.x; i < 4096; i += 256) { sW[i] = W[i]; sf[i] = fw[i]; }
  __syncthreads();
  for (int o = threadIdx.x; o < 4096; o += 256) {
    int i = o >> 6, j = o & 63;
    float acc = 0.f;
    #pragma unroll
    for (int k = 0; k < 64; ++k) acc += sW[i * 64 + k] * sf[k * 64 + j];
    sC[o] = acc;
  }
  __syncthreads();
  // B-fragment swizzle: frag f=(nt*2+kh), lane L, elem j -> B[(L>>4)*8+j+kh*32][nt*16+(L&15)]
  for (int o = threadIdx.x; o < 2048; o += 256) {
    int jj = o & 3, L = (o >> 2) & 63, kh = (o >> 8) & 1, nt = o >> 9;
    int k0 = (L >> 4) * 8 + jj * 2 + kh * 32;
    int n  = nt * 16 + (L & 15);
    unsigned int lo = f2h(sC[k0 * 64 + n]);
    unsigned int hi = f2h(sC[(k0 + 1) * 64 + n]);
    WcB[o] = (hi << 16) | lo;
  }
  if (threadIdx.x < 64) {
    int j = threadIdx.x;
    float acc = fb[j];
    #pragma unroll
    for (int k = 0; k < 64; ++k) acc += b[k] * sf[k * 64 + j];
    bc[j] = acc;
  }
}

// ---------------------------------------------------------------------------
// Pass 1: block-local counting sort of a 4096-edge chunk by 128-node bucket.
// R22 (verified in R8): wave shfl_up scan + wsum exchange (2 barriers).
// ---------------------------------------------------------------------------
__global__ __launch_bounds__(256) void pass1_sort(
    const int* __restrict__ src, const int* __restrict__ dst,
    unsigned int* __restrict__ stage, unsigned short* __restrict__ tbl) {
  __shared__ unsigned int hist[NBUCK];
  __shared__ unsigned int wsum4[4];
  __shared__ unsigned int sorted[P1_CHUNK];
  const int tid = threadIdx.x;
  const int wvid = tid >> 6, ln = tid & 63;
  const int e0 = blockIdx.x * P1_CHUNK;

  for (int b = tid; b < NBUCK; b += 256) hist[b] = 0;
  __syncthreads();

  int dreg[16];                               // dst cached -> no second dst read
  #pragma unroll
  for (int k = 0; k < 16; ++k) {
    int e = e0 + k * 256 + tid;
    int d = (e < N_EDGES) ? dst[e] : -1;
    dreg[k] = d;
    if (d >= 0) atomicAdd(&hist[((unsigned)d) >> BSHIFT], 1u);
  }
  __syncthreads();

  unsigned int v[4], run = 0;
  #pragma unroll
  for (int j = 0; j < 4; ++j) {
    int bk = 4 * tid + j;
    unsigned int h = (bk < NBUCK) ? hist[bk] : 0u;
    v[j] = run;
    run += h;
  }
  unsigned int inc = run;
  #pragma unroll
  for (int o = 1; o < 64; o <<= 1) {
    unsigned int t = __shfl_up(inc, o, 64);
    if (ln >= o) inc += t;
  }
  if (ln == 63) wsum4[wvid] = inc;
  __syncthreads();
  unsigned int wbase = 0, mtot = 0;
  #pragma unroll
  for (int k = 0; k < 4; ++k) {
    unsigned int s = wsum4[k];
    mtot += s;
    if (k < wvid) wbase += s;
  }
  const unsigned int excl = wbase + inc - run;
  const unsigned int m = mtot;
  unsigned short* trow = tbl + (size_t)blockIdx.x * TBL_STRIDE;
  #pragma unroll
  for (int j = 0; j < 4; ++j) {
    int bk = 4 * tid + j;
    if (bk < NBUCK) {
      unsigned int o = excl + v[j];
      hist[bk] = o;
      trow[bk] = (unsigned short)o;
    }
  }
  if (tid == 0) trow[NBUCK] = (unsigned short)m;
  __syncthreads();

  #pragma unroll
  for (int k = 0; k < 16; ++k) {
    int e = e0 + k * 256 + tid;
    int t = dreg[k];
    if (t >= 0) {
      unsigned int pos = atomicAdd(&hist[((unsigned)t) >> BSHIFT], 1u);
      sorted[pos] = (((unsigned)(t & (BNODES - 1))) << 17) | (unsigned)src[e];
    }
  }
  __syncthreads();

  unsigned int* so = stage + (size_t)blockIdx.x * P1_CHUNK;
  for (int i = tid; i < (int)m; i += 256) so[i] = sorted[i];
}

// ---------------------------------------------------------------------------
// Pass 2: paired-segment gather, LDS counting sort to node CSR. Emits eSrc,
// off, edeg, dinv, and the fused layer-1 prescale Xs (fp16).
// R22 (verified in R8): shfl_up scans, batch-4 MLP gather, float4 prescale.
// ---------------------------------------------------------------------------
__global__ __launch_bounds__(512) void pass2_sort(
    const unsigned int* __restrict__ stage, const unsigned short* __restrict__ tbl,
    int* __restrict__ eSrc, int* __restrict__ off, int* __restrict__ edeg,
    float* __restrict__ dinv, const float* __restrict__ x,
    unsigned short* __restrict__ Xs) {
  __shared__ int cnt[BNODES];
  __shared__ int wsum8[8];
  __shared__ int csum2[2];
  __shared__ float dinvL[BNODES];
  __shared__ unsigned int raw[BCAP];
  __shared__ int sorted[BCAP];
  const int b = blockIdx.x, tid = threadIdx.x;
  const int wvid = tid >> 6, ln = tid & 63;
  const int n0 = b * BNODES;

  int base0 = 0, base1 = 0, len0 = 0, len1 = 0;
  {
    int s0 = 2 * tid, s1 = 2 * tid + 1;
    if (s0 < NB_P1) {
      const unsigned short* trow = tbl + (size_t)s0 * TBL_STRIDE;
      int o0 = trow[b], o1 = trow[b + 1];
      base0 = s0 * P1_CHUNK + o0;
      len0 = o1 - o0;
    }
    if (s1 < NB_P1) {
      const unsigned short* trow = tbl + (size_t)s1 * TBL_STRIDE;
      int o0 = trow[b], o1 = trow[b + 1];
      base1 = s1 * P1_CHUNK + o0;
      len1 = o1 - o0;
    }
  }
  if (tid < BNODES) cnt[tid] = 0;
  const int mylen = len0 + len1;

  int inc = mylen;
  #pragma unroll
  for (int o = 1; o < 64; o <<= 1) {
    int t = __shfl_up(inc, o, 64);
    if (ln >= o) inc += t;
  }
  if (ln == 63) wsum8[wvid] = inc;
  __syncthreads();
  int wbase = 0, mtot = 0;
  #pragma unroll
  for (int k = 0; k < 8; ++k) {
    int s = wsum8[k];
    mtot += s;
    if (k < wvid) wbase += s;
  }
  const int m = mtot;
  const int pref = wbase + inc - mylen;

  // batch-4 gather: 4 loads issued before use -> 4x MLP on L2/L3 latency
  {
    int j = 0;
    for (; j + 4 <= len0; j += 4) {
      unsigned int p0 = stage[base0 + j],     p1 = stage[base0 + j + 1];
      unsigned int p2 = stage[base0 + j + 2], p3 = stage[base0 + j + 3];
      raw[pref + j] = p0; raw[pref + j + 1] = p1;
      raw[pref + j + 2] = p2; raw[pref + j + 3] = p3;
      atomicAdd(&cnt[p0 >> 17], 1); atomicAdd(&cnt[p1 >> 17], 1);
      atomicAdd(&cnt[p2 >> 17], 1); atomicAdd(&cnt[p3 >> 17], 1);
    }
    for (; j < len0; ++j) {
      unsigned int p = stage[base0 + j];
      raw[pref + j] = p;
      atomicAdd(&cnt[p >> 17], 1);
    }
  }
  {
    const int pb = pref + len0;
    int j = 0;
    for (; j + 4 <= len1; j += 4) {
      unsigned int p0 = stage[base1 + j],     p1 = stage[base1 + j + 1];
      unsigned int p2 = stage[base1 + j + 2], p3 = stage[base1 + j + 3];
      raw[pb + j] = p0; raw[pb + j + 1] = p1;
      raw[pb + j + 2] = p2; raw[pb + j + 3] = p3;
      atomicAdd(&cnt[p0 >> 17], 1); atomicAdd(&cnt[p1 >> 17], 1);
      atomicAdd(&cnt[p2 >> 17], 1); atomicAdd(&cnt[p3 >> 17], 1);
    }
    for (; j < len1; ++j) {
      unsigned int p = stage[base1 + j];
      raw[pb + j] = p;
      atomicAdd(&cnt[p >> 17], 1);
    }
  }
  __syncthreads();

  int v = (tid < BNODES) ? cnt[tid] : 0;
  int cin = v;
  #pragma unroll
  for (int o = 1; o < 64; o <<= 1) {
    int t = __shfl_up(cin, o, 64);
    if (ln >= o) cin += t;
  }
  if (tid < BNODES && ln == 63) csum2[wvid] = cin;
  __syncthreads();
  if (tid < BNODES) {
    int incl = cin + ((wvid == 1) ? csum2[0] : 0);
    int excl = incl - v;
    int node = n0 + tid;
    float dv = rsqrtf((float)v + 1.0f);
    dinvL[tid] = dv;
    if (node < N_NODES) {
      off[node]  = b * BCAP + excl;
      edeg[node] = v;
      dinv[node] = dv;
    }
    cnt[tid] = excl;
  }
  __syncthreads();

  for (int i = tid; i < m; i += 512) {
    unsigned int p = raw[i];
    int pos = atomicAdd(&cnt[p >> 17], 1);
    if (pos < BCAP) sorted[pos] = (int)(p & SRC_MASK);
  }
  __syncthreads();

  int* out = eSrc + (size_t)b * BCAP;
  for (int i = tid; i < m; i += 512) out[i] = sorted[i];

  const int rows = min(BNODES, N_NODES - n0);
  for (int i = tid; i < rows * 16; i += 512) {
    int r = i >> 4, c = i & 15;
    float4 xv = ((const float4*)x)[(size_t)(n0 + r) * 16 + c];
    float dv = dinvL[r];
    ushort4 o;
    o.x = f2h(dv * xv.x);
    o.y = f2h(dv * xv.y);
    o.z = f2h(dv * xv.z);
    o.w = f2h(dv * xv.w);
    ((ushort4*)Xs)[(size_t)(n0 + r) * 16 + c] = o;
  }
}

// ---------------------------------------------------------------------------
// CSR aggregation (v6, single dispatch, independent waves — the R7-verified
// form). At the random-gather L3-path wall: ~3.5 TB/s, ~49us, floor ~45us.
// R21: never barrier-couple gather waves. R24: split reverted (no visibility
// gain possible below the 41us harness fill).
// ---------------------------------------------------------------------------
__global__ __launch_bounds__(256) void agg_csr(
    const int* __restrict__ off, const int* __restrict__ edeg,
    const int* __restrict__ eSrc, const unsigned short* __restrict__ Xs,
    const float* __restrict__ dinv, unsigned short* __restrict__ agg) {
  const int wv = (blockIdx.x * 256 + threadIdx.x) >> 6;    // wave id
  const int lane = threadIdx.x & 63;
  const int half = lane >> 5;                              // node select
  const int l32 = lane & 31;
  const int grp = l32 >> 3;                                // 4 groups of 8
  const int sub = lane & 7;
  const int node = wv * 2 + half;
  if (node >= N_NODES) return;

  const int s0 = off[node];
  const int deg = edeg[node];
  const float dvf = dinv[node];                            // early, overlaps
  const uint4* XsV = (const uint4*)Xs;

  int eidx = node;
  if (deg > 0) {
    int li = (l32 < deg) ? l32 : deg - 1;
    eidx = __builtin_nontemporal_load(&eSrc[s0 + li]);
  }

  half2v acc[4];
  {
    uint4 u = XsV[(size_t)node * 8 + sub];
    if (l32 >= 8) { u.x = 0; u.y = 0; u.z = 0; u.w = 0; }
    acc[0] = u2h(u.x);
    acc[1] = u2h(u.y);
    acc[2] = u2h(u.z);
    acc[3] = u2h(u.w);
  }

  uint4 g[8];
  #pragma unroll
  for (int j = 0; j < 8; ++j) {
    int srcn = __shfl(eidx, half * 32 + j * 4 + grp, 64);
    g[j] = XsV[(size_t)srcn * 8 + sub];
  }
  #pragma unroll
  for (int j = 0; j < 8; ++j) {
    uint4 u = g[j];
    if (j * 4 + grp >= deg) { u.x = 0; u.y = 0; u.z = 0; u.w = 0; }
    addp(acc, u);
  }

  if (deg > 32) {                             // rare fallback
    const int lim = deg - 1;
    for (int e = 32; e < deg; e += 4) {
      int ee = e + grp;
      int srcn = __builtin_nontemporal_load(&eSrc[s0 + min(ee, lim)]);
      uint4 u = XsV[(size_t)srcn * 8 + sub];
      if (ee > lim) { u.x = 0; u.y = 0; u.z = 0; u.w = 0; }
      addp(acc, u);
    }
  }

  #pragma unroll
  for (int mk = 8; mk <= 16; mk <<= 1) {
    #pragma unroll
    for (int i = 0; i < 4; ++i)
      acc[i] += u2h(__shfl_xor(h2u(acc[i]), mk, 64));
  }

  if (l32 < 8) {
    _Float16 dh = (_Float16)dvf;
    half2v d2 = {dh, dh};
    u32x4 o;
    o.x = h2u(acc[0] * d2);
    o.y = h2u(acc[1] * d2);
    o.z = h2u(acc[2] * d2);
    o.w = h2u(acc[3] * d2);
    __builtin_nontemporal_store(o, (u32x4*)(agg + (size_t)node * 64 + sub * 8));
  }
}

// ---------------------------------------------------------------------------
// MFMA GEMM: Yb(fp16)[128-row block] = A(fp16) @ WcB + bc, fused col stats.
// Packed contiguous stat atomics (R12-proven; padding regresses ~40us).
// R23 lesson: grid-wide BN-stat dependency forces the kernel split here
// (cooperative launch silently no-ops under harness graph capture).
// ---------------------------------------------------------------------------
__global__ __launch_bounds__(256) void gemm_stats(
    const unsigned short* __restrict__ A, const unsigned int* __restrict__ WcB,
    const float* __restrict__ bc, unsigned short* __restrict__ Yb,
    float* __restrict__ colsum, float* __restrict__ colsq) {
  const int tid = threadIdx.x;
  const int L = tid & 63, wv = tid >> 6;
  const int quad = L >> 4, l16 = L & 15;

  const f16x8* Wv = (const f16x8*)WcB;
  f16x8 bfr[4][2];
  #pragma unroll
  for (int nt = 0; nt < 4; ++nt)
    #pragma unroll
    for (int kh = 0; kh < 2; ++kh)
      bfr[nt][kh] = Wv[(nt * 2 + kh) * 64 + L];
  float bcv[4];
  #pragma unroll
  for (int nt = 0; nt < 4; ++nt) bcv[nt] = bc[nt * 16 + l16];

  const f16x8* Av = (const f16x8*)A;
  float psum[4] = {0.f, 0.f, 0.f, 0.f}, psq[4] = {0.f, 0.f, 0.f, 0.f};

  #pragma unroll
  for (int loop = 0; loop < 2; ++loop) {
    const int rowbase = blockIdx.x * 128 + loop * 64 + wv * 16;
    const int m = min(rowbase + l16, N_NODES - 1);
    f16x8 a0 = Av[(size_t)m * 8 + quad];
    f16x8 a1 = Av[(size_t)m * 8 + 4 + quad];
    #pragma unroll
    for (int nt = 0; nt < 4; ++nt) {
      f32x4 acc = {0.f, 0.f, 0.f, 0.f};
      acc = __builtin_amdgcn_mfma_f32_16x16x32_f16(a0, bfr[nt][0], acc, 0, 0, 0);
      acc = __builtin_amdgcn_mfma_f32_16x16x32_f16(a1, bfr[nt][1], acc, 0, 0, 0);
      #pragma unroll
      for (int r = 0; r < 4; ++r) {
        int row = rowbase + quad * 4 + r;
        if (row < N_NODES) {
          float y = acc[r] + bcv[nt];
          Yb[(size_t)row * 64 + nt * 16 + l16] = f2h(y);
          psum[nt] += y;
          psq[nt] += y * y;
        }
      }
    }
  }

  #pragma unroll
  for (int nt = 0; nt < 4; ++nt) {
    psum[nt] += __shfl_xor(psum[nt], 16, 64);
    psum[nt] += __shfl_xor(psum[nt], 32, 64);
    psq[nt]  += __shfl_xor(psq[nt], 16, 64);
    psq[nt]  += __shfl_xor(psq[nt], 32, 64);
  }
  __shared__ float rsum[4][64];
  __shared__ float rsq[4][64];
  if (L < 16) {
    #pragma unroll
    for (int nt = 0; nt < 4; ++nt) {
      rsum[wv][nt * 16 + L] = psum[nt];
      rsq[wv][nt * 16 + L]  = psq[nt];
    }
  }
  __syncthreads();
  if (tid < 64) {
    float s = rsum[0][tid] + rsum[1][tid] + rsum[2][tid] + rsum[3][tid];
    float q = rsq[0][tid] + rsq[1][tid] + rsq[2][tid] + rsq[3][tid];
    atomicAdd(&colsum[tid], s);
    atomicAdd(&colsq[tid], q);
  }
}

// ---------------------------------------------------------------------------
// prescale_y (vectorized, uint4 = 8 fp16 per thread):
//   Xout = fp16( dinv[row] * relu(Yin*a1+c1) )
// ---------------------------------------------------------------------------
__global__ __launch_bounds__(256) void prescale_y(
    const unsigned short* __restrict__ Yin, unsigned short* __restrict__ Xout,
    const float* __restrict__ dinv,
    const float* __restrict__ colsum, const float* __restrict__ colsq,
    const float* __restrict__ g, const float* __restrict__ bt) {
  __shared__ float sa[64], sc[64];
  if (threadIdx.x < 64) {
    int j = threadIdx.x;
    float mu = colsum[j] * (1.0f / N_NODES);
    float var = colsq[j] * (1.0f / N_NODES) - mu * mu;
    float s = rsqrtf(var + EPS) * g[j];
    sa[j] = s;
    sc[j] = bt[j] - mu * s;
  }
  __syncthreads();
  int idx = blockIdx.x * blockDim.x + threadIdx.x;     // uint4 index
  if (idx < N_NODES * 8) {
    int r = idx >> 3, c0 = (idx & 7) * 8;
    float dv = dinv[r];
    uint4 u = ((const uint4*)Yin)[idx];
    float2 p0 = hpair(u.x), p1 = hpair(u.y), p2 = hpair(u.z), p3 = hpair(u.w);
    p0.x = dv * fmaxf(fmaf(p0.x, sa[c0    ], sc[c0    ]), 0.f);
    p0.y = dv * fmaxf(fmaf(p0.y, sa[c0 + 1], sc[c0 + 1]), 0.f);
    p1.x = dv * fmaxf(fmaf(p1.x, sa[c0 + 2], sc[c0 + 2]), 0.f);
    p1.y = dv * fmaxf(fmaf(p1.y, sa[c0 + 3], sc[c0 + 3]), 0.f);
    p2.x = dv * fmaxf(fmaf(p2.x, sa[c0 + 4], sc[c0 + 4]), 0.f);
    p2.y = dv * fmaxf(fmaf(p2.y, sa[c0 + 5], sc[c0 + 5]), 0.f);
    p3.x = dv * fmaxf(fmaf(p3.x, sa[c0 + 6], sc[c0 + 6]), 0.f);
    p3.y = dv * fmaxf(fmaf(p3.y, sa[c0 + 7], sc[c0 + 7]), 0.f);
    uint4 o;
    o.x = ((unsigned)f2h(p0.y) << 16) | f2h(p0.x);
    o.y = ((unsigned)f2h(p1.y) << 16) | f2h(p1.x);
    o.z = ((unsigned)f2h(p2.y) << 16) | f2h(p2.x);
    o.w = ((unsigned)f2h(p3.y) << 16) | f2h(p3.x);
    ((uint4*)Xout)[idx] = o;
  }
}

// ---------------------------------------------------------------------------
// final_norm (vectorized): out = fp32 relu(Yb*a2 + c2), 8 elems per thread
// ---------------------------------------------------------------------------
__global__ __launch_bounds__(256) void final_norm(
    const unsigned short* __restrict__ Yb, float* __restrict__ out,
    const float* __restrict__ colsum, const float* __restrict__ colsq,
    const float* __restrict__ g, const float* __restrict__ bt) {
  __shared__ float sa[64], sc[64];
  if (threadIdx.x < 64) {
    int j = threadIdx.x;
    float mu = colsum[j] * (1.0f / N_NODES);
    float var = colsq[j] * (1.0f / N_NODES) - mu * mu;
    float s = rsqrtf(var + EPS) * g[j];
    sa[j] = s;
    sc[j] = bt[j] - mu * s;
  }
  __syncthreads();
  int idx = blockIdx.x * blockDim.x + threadIdx.x;     // uint4 index
  if (idx < N_NODES * 8) {
    int c0 = (idx & 7) * 8;
    uint4 u = ((const uint4*)Yb)[idx];
    float2 p0 = hpair(u.x), p1 = hpair(u.y), p2 = hpair(u.z), p3 = hpair(u.w);
    float4 o0, o1;
    o0.x = fmaxf(fmaf(p0.x, sa[c0    ], sc[c0    ]), 0.f);
    o0.y = fmaxf(fmaf(p0.y, sa[c0 + 1], sc[c0 + 1]), 0.f);
    o0.z = fmaxf(fmaf(p1.x, sa[c0 + 2], sc[c0 + 2]), 0.f);
    o0.w = fmaxf(fmaf(p1.y, sa[c0 + 3], sc[c0 + 3]), 0.f);
    o1.x = fmaxf(fmaf(p2.x, sa[c0 + 4], sc[c0 + 4]), 0.f);
    o1.y = fmaxf(fmaf(p2.y, sa[c0 + 5], sc[c0 + 5]), 0.f);
    o1.z = fmaxf(fmaf(p3.x, sa[c0 + 6], sc[c0 + 6]), 0.f);
    o1.w = fmaxf(fmaf(p3.y, sa[c0 + 7], sc[c0 + 7]), 0.f);
    ((float4*)out)[idx * 2] = o0;
    ((float4*)out)[idx * 2 + 1] = o1;
  }
}

extern "C" void kernel_launch(void* const* d_in, const int* in_sizes, int n_in,
                              void* d_out, int out_size, void* d_ws, size_t ws_size,
                              hipStream_t stream) {
  const float* x   = (const float*)d_in[0];
  const int*   src = (const int*)d_in[1];          // edge_index row 0
  const int*   dst = src + N_EDGES;                // edge_index row 1
  const float* W1  = (const float*)d_in[2];
  const float* b1  = (const float*)d_in[3];
  const float* fw1 = (const float*)d_in[4];
  const float* fb1 = (const float*)d_in[5];
  const float* g1  = (const float*)d_in[6];
  const float* bt1 = (const float*)d_in[7];
  const float* W2  = (const float*)d_in[8];
  const float* b2  = (const float*)d_in[9];
  const float* fw2 = (const float*)d_in[10];
  const float* fb2 = (const float*)d_in[11];
  const float* g2  = (const float*)d_in[12];
  const float* bt2 = (const float*)d_in[13];

  float* out = (float*)d_out;                      // N x 64 fp32

  // workspace (~43 MB). aggb aliases stage; XsYb doubles as the fp16 Y buffer.
  unsigned char* w = (unsigned char*)d_ws;
  unsigned int*   stage = (unsigned int*)w;              // NB_P1*4096 uints
  unsigned short* aggb  = (unsigned short*)w;            // N*64 fp16 (alias)
  size_t ofs = ((size_t)NB_P1 * P1_CHUNK * 4 + 255) & ~(size_t)255;
  float*          dinv  = (float*)(w + ofs);             // N floats
  unsigned short* XsYb  = (unsigned short*)(dinv + N_NODES);          // N*64 fp16
  int*            eSrc  = (int*)(XsYb + (size_t)N_NODES * D);         // NBUCK*BCAP ints
  int*            off   = eSrc + (size_t)NBUCK * BCAP;   // N ints
  int*            edeg  = off + N_NODES;                 // N ints
  unsigned short* tbl   = (unsigned short*)(edeg + N_NODES);          // NB_P1*784 ushort
  unsigned int* WcB1 = (unsigned int*)(tbl + (size_t)NB_P1 * TBL_STRIDE); // 2048
  float* bc1  = (float*)(WcB1 + 2048);             // 64
  unsigned int* WcB2 = (unsigned int*)(bc1 + 64);  // 2048
  float* bc2  = (float*)(WcB2 + 2048);             // 64
  float* sum1 = bc2 + 64;                          // 64  (sum1..sq2 contiguous 256)
  float* sq1  = sum1 + 64;
  float* sum2 = sq1 + 64;
  float* sq2  = sum2 + 64;

  const int nv = N_NODES * 8;                      // uint4 count for elementwise
  const int nagg = (N_NODES + 7) / 8;              // 12500: 4 waves x 2 nodes
  dim3 blk(256);

  // 1. weight fold + stats zero (3 blocks)
  combine_weights<<<3, blk, 0, stream>>>(W1, b1, fw1, fb1, W2, b2, fw2, fb2,
                                         WcB1, bc1, WcB2, bc2, sum1);
  // 2-3. partition: block-local sort -> per-bucket node CSR (+L1 prescale)
  pass1_sort<<<NB_P1, blk, 0, stream>>>(src, dst, stage, tbl);
  pass2_sort<<<NBUCK, 512, 0, stream>>>(stage, tbl, eSrc, off, edeg, dinv, x, XsYb);
  // 4-6. layer 1
  agg_csr<<<nagg, blk, 0, stream>>>(off, edeg, eSrc, XsYb, dinv, aggb);
  gemm_stats<<<(N_NODES + 127) / 128, blk, 0, stream>>>(aggb, WcB1, bc1, XsYb, sum1, sq1);
  prescale_y<<<(nv + 255) / 256, blk, 0, stream>>>(XsYb, XsYb, dinv, sum1, sq1, g1, bt1);
  // 7-9. layer 2
  agg_csr<<<nagg, blk, 0, stream>>>(off, edeg, eSrc, XsYb, dinv, aggb);
  gemm_stats<<<(N_NODES + 127) / 128, blk, 0, stream>>>(aggb, WcB2, bc2, XsYb, sum2, sq2);
  final_norm<<<(nv + 255) / 256, blk, 0, stream>>>(XsYb, out, sum2, sq2, g2, bt2);
}